// Round 8
// baseline (248.507 us; speedup 1.0000x reference)
//
#include <hip/hip_runtime.h>
#include <hip/hip_bf16.h>

// Spectral attention: B=2, N=50000, D=256, H=8, Dh=32, K_EIG=32, NUM_BANDS=3
// Key identity: Qf = E^T (x Wq^T + bq) = (E^T x) Wq^T + s * bq, s[k] = sum_n E[n,k]
// N-sized work: U = E^T x (read x once) and out = E @ out_freq (write out once).
// Lessons: r2 = per-thread arrays spill (named regs only); r3 = no redundant
// HBM x reads; r4 = >=4 blocks/CU; r5 = stage E in LDS; r6 = deep prefetch;
// r7 = waves must own DISJOINT x rows (4x redundant L1 loads + per-wave
// latency chains kept k_partial latency-bound at VALUBusy 22%).

constexpr int D = 256;   // d_model

// ---------------------------------------------------------------- k_colsum
__global__ __launch_bounds__(256) void k_colsum(const float* __restrict__ E,
                                                float* __restrict__ pS, int N) {
  int k = threadIdx.x & 31;
  int rg = threadIdx.x >> 5;
  int rs = (N + 255) >> 8;
  int n0 = blockIdx.x * rs;
  int n1 = n0 + rs; if (n1 > N) n1 = N;
  float acc = 0.f;
  for (int n = n0 + rg; n < n1; n += 8) acc += E[(size_t)n * 32 + k];
  __shared__ float red[256];
  red[threadIdx.x] = acc;
  __syncthreads();
  if (threadIdx.x < 32) {
    float t = red[threadIdx.x];
#pragma unroll
    for (int i = 1; i < 8; ++i) t += red[i * 32 + threadIdx.x];
    pS[blockIdx.x * 32 + threadIdx.x] = t;
  }
}

// ---------------------------------------------------------------- k_partial
// grid = B * nchunk * 2 (d-half). Wave ro owns rows ro, ro+4, ... of the chunk
// (disjoint!); lane owns d-pair. 32 float2 named accumulators; E tile in LDS
// (broadcast b128 reads); 8-deep x prefetch. Cross-wave LDS octet reduce ->
// one [32][128] partial per block. pU[(b*nchunk+c)*2+dh][k][dl].
__global__ __launch_bounds__(256, 4) void k_partial(const float* __restrict__ x,
                                                    const float* __restrict__ E,
                                                    float* __restrict__ pU,
                                                    int N, int nchunk, int rpc) {
  int blk = blockIdx.x;
  int dh = blk & 1;
  int bc = blk >> 1;                       // b*nchunk + c
  int c = bc % nchunk;
  int b = bc / nchunk;
  int t = threadIdx.x;
  int ro = t >> 6;                         // wave id = row phase 0..3
  int lane = t & 63;
  int n0 = c * rpc;
  int n1 = n0 + rpc; if (n1 > N) n1 = N;
  int nrows = n1 - n0; if (nrows < 0) nrows = 0;

  __shared__ __align__(16) float smem[4096];   // 16KB: E tile, then reduce buf

  if (nrows > 0) {  // stage E tile [nrows][32]
    const float4* Esrc = reinterpret_cast<const float4*>(E + (size_t)n0 * 32);
    float4* Edst = reinterpret_cast<float4*>(smem);
    int nf4 = nrows * 8;
    for (int i = t; i < nf4; i += 256) Edst[i] = Esrc[i];
  }
  __syncthreads();

  float2 a0={0,0},a1={0,0},a2={0,0},a3={0,0},a4={0,0},a5={0,0},a6={0,0},a7={0,0};
  float2 a8={0,0},a9={0,0},a10={0,0},a11={0,0},a12={0,0},a13={0,0},a14={0,0},a15={0,0};
  float2 a16={0,0},a17={0,0},a18={0,0},a19={0,0},a20={0,0},a21={0,0},a22={0,0},a23={0,0};
  float2 a24={0,0},a25={0,0},a26={0,0},a27={0,0},a28={0,0},a29={0,0},a30={0,0},a31={0,0};

  int mrows = (nrows > ro) ? ((nrows - ro + 3) >> 2) : 0;   // rows for this wave

  if (mrows > 0) {
    const float* xb = x + (size_t)b * N * D + dh * 128 + 2 * lane;
#define XLD(j) (*reinterpret_cast<const float2*>( \
    xb + (size_t)(n0 + ro + 4 * ((j) < mrows ? (j) : mrows - 1)) * D))

    float2 p0 = XLD(0), p1 = XLD(1), p2 = XLD(2), p3 = XLD(3);
    float2 p4 = XLD(4), p5 = XLD(5), p6 = XLD(6), p7 = XLD(7);

#define FMAK(e, aA, aB, aC, aD)                                   \
  aA.x = fmaf(e.x, xq.x, aA.x); aA.y = fmaf(e.x, xq.y, aA.y);     \
  aB.x = fmaf(e.y, xq.x, aB.x); aB.y = fmaf(e.y, xq.y, aB.y);     \
  aC.x = fmaf(e.z, xq.x, aC.x); aC.y = fmaf(e.z, xq.y, aC.y);     \
  aD.x = fmaf(e.w, xq.x, aD.x); aD.y = fmaf(e.w, xq.y, aD.y);

#define ROW1(j, q) {                                              \
    const float4* eb = reinterpret_cast<const float4*>(           \
        smem + (ro + 4 * (j)) * 32);                              \
    float4 e0 = eb[0], e1 = eb[1], e2 = eb[2], e3 = eb[3];        \
    float4 e4 = eb[4], e5 = eb[5], e6 = eb[6], e7 = eb[7];        \
    float2 xq = q;                                                \
    FMAK(e0, a0,  a1,  a2,  a3)  FMAK(e1, a4,  a5,  a6,  a7)      \
    FMAK(e2, a8,  a9,  a10, a11) FMAK(e3, a12, a13, a14, a15)     \
    FMAK(e4, a16, a17, a18, a19) FMAK(e5, a20, a21, a22, a23)     \
    FMAK(e6, a24, a25, a26, a27) FMAK(e7, a28, a29, a30, a31) }

    int j = 0;
#pragma unroll 1
    for (; j + 8 <= mrows; j += 8) {
      ROW1(j + 0, p0) ROW1(j + 1, p1) ROW1(j + 2, p2) ROW1(j + 3, p3)
      p0 = XLD(j + 8);  p1 = XLD(j + 9);  p2 = XLD(j + 10); p3 = XLD(j + 11);
      ROW1(j + 4, p4) ROW1(j + 5, p5) ROW1(j + 6, p6) ROW1(j + 7, p7)
      p4 = XLD(j + 12); p5 = XLD(j + 13); p6 = XLD(j + 14); p7 = XLD(j + 15);
    }
    int rem = mrows - j;                   // 0..7, rows j..j+rem-1 in p0..p6
    if (rem > 0) ROW1(j + 0, p0)
    if (rem > 1) ROW1(j + 1, p1)
    if (rem > 2) ROW1(j + 2, p2)
    if (rem > 3) ROW1(j + 3, p3)
    if (rem > 4) ROW1(j + 4, p4)
    if (rem > 5) ROW1(j + 5, p5)
    if (rem > 6) ROW1(j + 6, p6)
#undef ROW1
#undef FMAK
#undef XLD
  }

  // cross-wave reduce (4 waves -> 1) in 4 octet passes; rb = [ro][kk][lane] f2
  float2* rb = reinterpret_cast<float2*>(smem);
  float* o = pU + ((size_t)bc * 2 + dh) * 4096;

#define OCT(g, cA, cB, cC, cD, cE, cF, cG, cH)                    \
  __syncthreads();                                                \
  rb[(ro * 8 + 0) * 64 + lane] = cA; rb[(ro * 8 + 1) * 64 + lane] = cB; \
  rb[(ro * 8 + 2) * 64 + lane] = cC; rb[(ro * 8 + 3) * 64 + lane] = cD; \
  rb[(ro * 8 + 4) * 64 + lane] = cE; rb[(ro * 8 + 5) * 64 + lane] = cF; \
  rb[(ro * 8 + 6) * 64 + lane] = cG; rb[(ro * 8 + 7) * 64 + lane] = cH; \
  __syncthreads();                                                \
  _Pragma("unroll")                                               \
  for (int i = 0; i < 2; ++i) {                                   \
    int idx = i * 256 + t;                                        \
    int kk = idx >> 6, ll = idx & 63;                             \
    float2 s0 = rb[(0 * 8 + kk) * 64 + ll], s1 = rb[(1 * 8 + kk) * 64 + ll]; \
    float2 s2 = rb[(2 * 8 + kk) * 64 + ll], s3 = rb[(3 * 8 + kk) * 64 + ll]; \
    float2 sv;                                                    \
    sv.x = (s0.x + s1.x) + (s2.x + s3.x);                         \
    sv.y = (s0.y + s1.y) + (s2.y + s3.y);                         \
    *reinterpret_cast<float2*>(o + ((g) * 8 + kk) * 128 + 2 * ll) = sv; \
  }

  OCT(0, a0,  a1,  a2,  a3,  a4,  a5,  a6,  a7)
  OCT(1, a8,  a9,  a10, a11, a12, a13, a14, a15)
  OCT(2, a16, a17, a18, a19, a20, a21, a22, a23)
  OCT(3, a24, a25, a26, a27, a28, a29, a30, a31)
#undef OCT
}

// ---------------------------------------------------------------- k_reduce
// U[b,k,d] = sum_c pU[(b*nchunk+c)*2+dh][k][dl]; 512 blocks, 8 subs x 4 accs.
__global__ __launch_bounds__(256) void k_reduce(const float* __restrict__ pU,
                                                float* __restrict__ U, int nchunk) {
  int e = blockIdx.x * 32 + (threadIdx.x & 31);
  int sub = threadIdx.x >> 5;              // 0..7
  int b = e >> 13;
  int kd = e & 8191;
  int k = kd >> 8;
  int d = kd & 255;
  int dh = d >> 7, dl = d & 127;
  const float* p = pU + (size_t)b * nchunk * 8192 + (size_t)dh * 4096 + k * 128 + dl;
  float a0 = 0.f, a1 = 0.f, a2 = 0.f, a3 = 0.f;
  int c = sub;
#pragma unroll 1
  for (; c + 24 < nchunk; c += 32) {
    a0 += p[(size_t)c * 8192];
    a1 += p[(size_t)(c + 8) * 8192];
    a2 += p[(size_t)(c + 16) * 8192];
    a3 += p[(size_t)(c + 24) * 8192];
  }
  for (; c < nchunk; c += 8) a0 += p[(size_t)c * 8192];
  __shared__ float red[256];
  red[threadIdx.x] = (a0 + a1) + (a2 + a3);
  __syncthreads();
  if (threadIdx.x < 32) {
    float s = red[threadIdx.x];
#pragma unroll
    for (int i = 1; i < 8; ++i) s += red[i * 32 + threadIdx.x];
    U[e] = s;
  }
}

// ---------------------------------------------------------------- k_project
__global__ __launch_bounds__(256) void k_project(
    const float* __restrict__ U, const float* __restrict__ pS,
    const float* __restrict__ Wq, const float* __restrict__ bq,
    const float* __restrict__ Wk, const float* __restrict__ bk,
    const float* __restrict__ Wv, const float* __restrict__ bv,
    const float* __restrict__ ev, const float* __restrict__ bb,
    const float* __restrict__ fw,
    float* __restrict__ Qfg, float* __restrict__ Kfg, float* __restrict__ Vfg) {
  int blk = blockIdx.x;                    // b*32 + k
  int k = blk & 31;
  int t = threadIdx.x;
  __shared__ __align__(16) float u[256];
  __shared__ float red[256];
  u[t] = U[(size_t)blk * 256 + t];
  red[t] = pS[t * 32 + k];
  __syncthreads();
#pragma unroll
  for (int off = 128; off > 0; off >>= 1) {
    if (t < off) red[t] += red[t + off];
    __syncthreads();
  }
  float sk = red[0];

  // filter response — FP64 to match numpy ref branch semantics
  float mnf = ev[0], mxf = ev[0];
#pragma unroll
  for (int i = 1; i < 32; ++i) { float v = ev[i]; mnf = fminf(mnf, v); mxf = fmaxf(mxf, v); }
  double mn = (double)mnf, mx = (double)mxf;
  double lam = ((double)ev[k] - mn) / (mx - mn + 1e-8);
  int h = t >> 5;
  float g = 0.f;
#pragma unroll
  for (int i = 0; i < 3; ++i) {
    double lo = (double)bb[h * 4 + i], hi = (double)bb[h * 4 + i + 1];
    if (lam >= lo && lam < hi) g = fw[(h * 3 + i) * 32 + k];
  }

  const float4* u4 = reinterpret_cast<const float4*>(u);
  const float4* wq4 = reinterpret_cast<const float4*>(Wq) + (size_t)t * 64;
  const float4* wk4 = reinterpret_cast<const float4*>(Wk) + (size_t)t * 64;
  const float4* wv4 = reinterpret_cast<const float4*>(Wv) + (size_t)t * 64;
  float aq = 0.f, ak = 0.f, av = 0.f;
#pragma unroll 4
  for (int j = 0; j < 64; ++j) {
    float4 uv = u4[j];
    float4 q = wq4[j], kk = wk4[j], vv = wv4[j];
    aq = fmaf(uv.x, q.x, aq);  aq = fmaf(uv.y, q.y, aq);
    aq = fmaf(uv.z, q.z, aq);  aq = fmaf(uv.w, q.w, aq);
    ak = fmaf(uv.x, kk.x, ak); ak = fmaf(uv.y, kk.y, ak);
    ak = fmaf(uv.z, kk.z, ak); ak = fmaf(uv.w, kk.w, ak);
    av = fmaf(uv.x, vv.x, av); av = fmaf(uv.y, vv.y, av);
    av = fmaf(uv.z, vv.z, av); av = fmaf(uv.w, vv.w, av);
  }
  Qfg[(size_t)blk * 256 + t] = (aq + bq[t] * sk) * g;
  Kfg[(size_t)blk * 256 + t] = (ak + bk[t] * sk) * g;
  Vfg[(size_t)blk * 256 + t] = (av + bv[t] * sk) * g;
}

// ---------------------------------------------------------------- k_attn
__global__ __launch_bounds__(1024) void k_attn(const float* __restrict__ Qfg,
                                               const float* __restrict__ Kfg,
                                               const float* __restrict__ Vfg,
                                               float* __restrict__ of) {
  int blk = blockIdx.x;                    // b*8 + h
  int b = blk >> 3, h = blk & 7;
  int tid = threadIdx.x;
  int row = tid >> 5, col = tid & 31;
  __shared__ float Q[32][33], Kt[32][33], V[32][33], A[32][33];
  size_t base = (size_t)b * 32 * 256 + h * 32;
  Q[row][col]  = Qfg[base + row * 256 + col];
  Kt[row][col] = Kfg[base + row * 256 + col];
  V[row][col]  = Vfg[base + row * 256 + col];
  __syncthreads();
  float sc = 0.f;
#pragma unroll
  for (int d0 = 0; d0 < 32; ++d0) sc = fmaf(Q[row][d0], Kt[col][d0], sc);
  sc *= 0.17677669529663687f;              // 1/sqrt(32)
  float m = sc;
#pragma unroll
  for (int o = 16; o > 0; o >>= 1) m = fmaxf(m, __shfl_xor(m, o, 32));
  float p = expf(sc - m);
  float su = p;
#pragma unroll
  for (int o = 16; o > 0; o >>= 1) su += __shfl_xor(su, o, 32);
  A[row][col] = p / su;
  __syncthreads();
  float o_ = 0.f;
#pragma unroll
  for (int l = 0; l < 32; ++l) o_ = fmaf(A[row][l], V[l][col], o_);
  of[base + row * 256 + col] = o_;
}

// ---------------------------------------------------------------- k_expand
// out[b,n,d] = sum_k E[n,k] * of[b,k,d]. Thread owns d=t, computes BOTH b
// (of in 32 float2 regs). E tile in LDS, broadcast ds_read per row.
__global__ __launch_bounds__(256) void k_expand(const float* __restrict__ E,
                                                const float* __restrict__ of,
                                                float* __restrict__ out,
                                                int N, int rows) {
  int n0 = blockIdx.x * rows;
  int n1 = n0 + rows; if (n1 > N) n1 = N;
  int nrows = n1 - n0;
  if (nrows <= 0) return;
  int t = threadIdx.x;

  const float* ofb = of + t;               // fk = {of[0][k][t], of[1][k][t]}
#define LDF(i) float2 f##i = make_float2(ofb[(i) * 256], ofb[8192 + (i) * 256]);
  LDF(0)  LDF(1)  LDF(2)  LDF(3)  LDF(4)  LDF(5)  LDF(6)  LDF(7)
  LDF(8)  LDF(9)  LDF(10) LDF(11) LDF(12) LDF(13) LDF(14) LDF(15)
  LDF(16) LDF(17) LDF(18) LDF(19) LDF(20) LDF(21) LDF(22) LDF(23)
  LDF(24) LDF(25) LDF(26) LDF(27) LDF(28) LDF(29) LDF(30) LDF(31)
#undef LDF

  __shared__ __align__(16) float Elds[50 * 32];    // rows <= 50
  {
    const float4* Esrc = reinterpret_cast<const float4*>(E + (size_t)n0 * 32);
    float4* Edst = reinterpret_cast<float4*>(Elds);
    int nf4 = nrows * 8;
    for (int i = t; i < nf4; i += 256) Edst[i] = Esrc[i];
  }
  __syncthreads();

  float* o0 = out + t;
  float* o1 = out + (size_t)N * D + t;

#define EXP2(s, fk) { acc0 = fmaf(s, fk.x, acc0); acc1 = fmaf(s, fk.y, acc1); }
#pragma unroll 1
  for (int i = 0; i < nrows; ++i) {
    const float4* er = reinterpret_cast<const float4*>(Elds + i * 32);
    float4 e0 = er[0], e1 = er[1], e2 = er[2], e3 = er[3];
    float4 e4 = er[4], e5 = er[5], e6 = er[6], e7 = er[7];
    float acc0 = 0.f, acc1 = 0.f;
    EXP2(e0.x, f0)  EXP2(e0.y, f1)  EXP2(e0.z, f2)  EXP2(e0.w, f3)
    EXP2(e1.x, f4)  EXP2(e1.y, f5)  EXP2(e1.z, f6)  EXP2(e1.w, f7)
    EXP2(e2.x, f8)  EXP2(e2.y, f9)  EXP2(e2.z, f10) EXP2(e2.w, f11)
    EXP2(e3.x, f12) EXP2(e3.y, f13) EXP2(e3.z, f14) EXP2(e3.w, f15)
    EXP2(e4.x, f16) EXP2(e4.y, f17) EXP2(e4.z, f18) EXP2(e4.w, f19)
    EXP2(e5.x, f20) EXP2(e5.y, f21) EXP2(e5.z, f22) EXP2(e5.w, f23)
    EXP2(e6.x, f24) EXP2(e6.y, f25) EXP2(e6.z, f26) EXP2(e6.w, f27)
    EXP2(e7.x, f28) EXP2(e7.y, f29) EXP2(e7.z, f30) EXP2(e7.w, f31)
    size_t roff = (size_t)(n0 + i) * D;
    o0[roff] = acc0;
    o1[roff] = acc1;
  }
#undef EXP2
}

// ---------------------------------------------------------------- launch
extern "C" void kernel_launch(void* const* d_in, const int* in_sizes, int n_in,
                              void* d_out, int out_size, void* d_ws, size_t ws_size,
                              hipStream_t stream) {
  const float* x  = (const float*)d_in[0];
  const float* E  = (const float*)d_in[1];
  const float* ev = (const float*)d_in[2];
  const float* Wq = (const float*)d_in[3];
  const float* bq = (const float*)d_in[4];
  const float* Wk = (const float*)d_in[5];
  const float* bk = (const float*)d_in[6];
  const float* Wv = (const float*)d_in[7];
  const float* bv = (const float*)d_in[8];
  const float* bb = (const float*)d_in[9];
  const float* fw = (const float*)d_in[10];
  float* out = (float*)d_out;
  float* ws  = (float*)d_ws;

  const int N = in_sizes[1] / 32;          // 50000
  const int B = in_sizes[0] / (N * 256);   // 2

  // workspace layout (floats)
  float* U   = ws;                         // B*32*256 = 16384
  float* Qfg = ws + 16384;
  float* Kfg = ws + 32768;
  float* Vfg = ws + 49152;
  float* of  = ws + 65536;
  float* pS  = ws + 81920;                 // 256*32 = 8192
  float* pU  = ws + 90112;                 // B*nchunk*2*4096 floats

  // nchunk = 512 -> grid 2048 (8 blocks/CU), pU 33.6 MB (fit since r6).
  int nchunk = 512;
  if ((90112 + (size_t)B * nchunk * 8192) * sizeof(float) > ws_size) nchunk = 256;
  int rpc = (N + nchunk - 1) / nchunk;

  k_colsum<<<256, 256, 0, stream>>>(E, pS, N);
  k_partial<<<B * nchunk * 2, 256, 0, stream>>>(x, E, pU, N, nchunk, rpc);
  k_reduce<<<B * 8192 / 32, 256, 0, stream>>>(pU, U, nchunk);
  k_project<<<B * 32, 256, 0, stream>>>(U, pS, Wq, bq, Wk, bk, Wv, bv,
                                        ev, bb, fw, Qfg, Kfg, Vfg);
  k_attn<<<B * 8, 1024, 0, stream>>>(Qfg, Kfg, Vfg, of);
  int rows = 50;
  int nbr = (N + rows - 1) / rows;
  k_expand<<<nbr, 256, 0, stream>>>(E, of, out, N, rows);
}

// Round 9
// 120.375 us; speedup vs baseline: 2.0644x; 2.0644x over previous
//
#include <hip/hip_runtime.h>
#include <hip/hip_bf16.h>

// Spectral attention: B=2, N=50000, D=256, H=8, Dh=32, K_EIG=32, NUM_BANDS=3
// Key identity: Qf = E^T (x Wq^T + bq) = (E^T x) Wq^T + s * bq, s[k] = sum_n E[n,k]
// N-sized work: U = E^T x (read x once) and out = E @ out_freq (write out once).
// Lessons: r2 = per-thread arrays spill (named regs only); r3 = no redundant
// HBM x reads; r4 = >=4 blocks/CU; r5 = stage E in LDS; r6 = deep prefetch;
// r7 = waves own DISJOINT x rows; r8 = __launch_bounds__ min-waves arg capped
// VGPR at 64 -> accumulators spilled in the hot loop (WRITE_SIZE 390MB!).
// NEVER set the min-waves arg on a register-heavy kernel.

constexpr int D = 256;   // d_model

// ---------------------------------------------------------------- k_colsum
__global__ __launch_bounds__(256) void k_colsum(const float* __restrict__ E,
                                                float* __restrict__ pS, int N) {
  int k = threadIdx.x & 31;
  int rg = threadIdx.x >> 5;
  int rs = (N + 255) >> 8;
  int n0 = blockIdx.x * rs;
  int n1 = n0 + rs; if (n1 > N) n1 = N;
  float acc = 0.f;
  for (int n = n0 + rg; n < n1; n += 8) acc += E[(size_t)n * 32 + k];
  __shared__ float red[256];
  red[threadIdx.x] = acc;
  __syncthreads();
  if (threadIdx.x < 32) {
    float t = red[threadIdx.x];
#pragma unroll
    for (int i = 1; i < 8; ++i) t += red[i * 32 + threadIdx.x];
    pS[blockIdx.x * 32 + threadIdx.x] = t;
  }
}

// ---------------------------------------------------------------- k_partial
// grid = B * nchunk * 2 (d-half). Wave ro owns rows ro, ro+4, ... of the chunk
// (disjoint); lane owns d-pair. 32 float2 named accumulators; E tile in LDS
// (broadcast b128 reads); 8-deep x prefetch. Cross-wave LDS octet reduce ->
// one [32][128] partial per block. pU[(b*nchunk+c)*2+dh][k][dl].
// NOTE: no min-waves in launch_bounds — needs ~140 VGPR, a cap spills (r8).
__global__ __launch_bounds__(256) void k_partial(const float* __restrict__ x,
                                                 const float* __restrict__ E,
                                                 float* __restrict__ pU,
                                                 int N, int nchunk, int rpc) {
  int blk = blockIdx.x;
  int dh = blk & 1;
  int bc = blk >> 1;                       // b*nchunk + c
  int c = bc % nchunk;
  int b = bc / nchunk;
  int t = threadIdx.x;
  int ro = t >> 6;                         // wave id = row phase 0..3
  int lane = t & 63;
  int n0 = c * rpc;
  int n1 = n0 + rpc; if (n1 > N) n1 = N;
  int nrows = n1 - n0; if (nrows < 0) nrows = 0;

  __shared__ __align__(16) float smem[4096];   // 16KB: E tile, then reduce buf

  if (nrows > 0) {  // stage E tile [nrows][32]
    const float4* Esrc = reinterpret_cast<const float4*>(E + (size_t)n0 * 32);
    float4* Edst = reinterpret_cast<float4*>(smem);
    int nf4 = nrows * 8;
    for (int i = t; i < nf4; i += 256) Edst[i] = Esrc[i];
  }
  __syncthreads();

  float2 a0={0,0},a1={0,0},a2={0,0},a3={0,0},a4={0,0},a5={0,0},a6={0,0},a7={0,0};
  float2 a8={0,0},a9={0,0},a10={0,0},a11={0,0},a12={0,0},a13={0,0},a14={0,0},a15={0,0};
  float2 a16={0,0},a17={0,0},a18={0,0},a19={0,0},a20={0,0},a21={0,0},a22={0,0},a23={0,0};
  float2 a24={0,0},a25={0,0},a26={0,0},a27={0,0},a28={0,0},a29={0,0},a30={0,0},a31={0,0};

  int mrows = (nrows > ro) ? ((nrows - ro + 3) >> 2) : 0;   // rows for this wave

  if (mrows > 0) {
    const float* xb = x + (size_t)b * N * D + dh * 128 + 2 * lane;
#define XLD(j) (*reinterpret_cast<const float2*>( \
    xb + (size_t)(n0 + ro + 4 * ((j) < mrows ? (j) : mrows - 1)) * D))

    float2 p0 = XLD(0), p1 = XLD(1), p2 = XLD(2), p3 = XLD(3);
    float2 p4 = XLD(4), p5 = XLD(5), p6 = XLD(6), p7 = XLD(7);

#define FMAK(e, aA, aB, aC, aD)                                   \
  aA.x = fmaf(e.x, xq.x, aA.x); aA.y = fmaf(e.x, xq.y, aA.y);     \
  aB.x = fmaf(e.y, xq.x, aB.x); aB.y = fmaf(e.y, xq.y, aB.y);     \
  aC.x = fmaf(e.z, xq.x, aC.x); aC.y = fmaf(e.z, xq.y, aC.y);     \
  aD.x = fmaf(e.w, xq.x, aD.x); aD.y = fmaf(e.w, xq.y, aD.y);

#define ROW1(j, q) {                                              \
    const float4* eb = reinterpret_cast<const float4*>(           \
        smem + (ro + 4 * (j)) * 32);                              \
    float4 e0 = eb[0], e1 = eb[1], e2 = eb[2], e3 = eb[3];        \
    float4 e4 = eb[4], e5 = eb[5], e6 = eb[6], e7 = eb[7];        \
    float2 xq = q;                                                \
    FMAK(e0, a0,  a1,  a2,  a3)  FMAK(e1, a4,  a5,  a6,  a7)      \
    FMAK(e2, a8,  a9,  a10, a11) FMAK(e3, a12, a13, a14, a15)     \
    FMAK(e4, a16, a17, a18, a19) FMAK(e5, a20, a21, a22, a23)     \
    FMAK(e6, a24, a25, a26, a27) FMAK(e7, a28, a29, a30, a31) }

    int j = 0;
#pragma unroll 1
    for (; j + 8 <= mrows; j += 8) {
      ROW1(j + 0, p0) ROW1(j + 1, p1) ROW1(j + 2, p2) ROW1(j + 3, p3)
      p0 = XLD(j + 8);  p1 = XLD(j + 9);  p2 = XLD(j + 10); p3 = XLD(j + 11);
      ROW1(j + 4, p4) ROW1(j + 5, p5) ROW1(j + 6, p6) ROW1(j + 7, p7)
      p4 = XLD(j + 12); p5 = XLD(j + 13); p6 = XLD(j + 14); p7 = XLD(j + 15);
    }
    int rem = mrows - j;                   // 0..7, rows j..j+rem-1 in p0..p6
    if (rem > 0) ROW1(j + 0, p0)
    if (rem > 1) ROW1(j + 1, p1)
    if (rem > 2) ROW1(j + 2, p2)
    if (rem > 3) ROW1(j + 3, p3)
    if (rem > 4) ROW1(j + 4, p4)
    if (rem > 5) ROW1(j + 5, p5)
    if (rem > 6) ROW1(j + 6, p6)
#undef ROW1
#undef FMAK
#undef XLD
  }

  // cross-wave reduce (4 waves -> 1) in 4 octet passes; rb = [ro][kk][lane] f2
  float2* rb = reinterpret_cast<float2*>(smem);
  float* o = pU + ((size_t)bc * 2 + dh) * 4096;

#define OCT(g, cA, cB, cC, cD, cE, cF, cG, cH)                    \
  __syncthreads();                                                \
  rb[(ro * 8 + 0) * 64 + lane] = cA; rb[(ro * 8 + 1) * 64 + lane] = cB; \
  rb[(ro * 8 + 2) * 64 + lane] = cC; rb[(ro * 8 + 3) * 64 + lane] = cD; \
  rb[(ro * 8 + 4) * 64 + lane] = cE; rb[(ro * 8 + 5) * 64 + lane] = cF; \
  rb[(ro * 8 + 6) * 64 + lane] = cG; rb[(ro * 8 + 7) * 64 + lane] = cH; \
  __syncthreads();                                                \
  _Pragma("unroll")                                               \
  for (int i = 0; i < 2; ++i) {                                   \
    int idx = i * 256 + t;                                        \
    int kk = idx >> 6, ll = idx & 63;                             \
    float2 s0 = rb[(0 * 8 + kk) * 64 + ll], s1 = rb[(1 * 8 + kk) * 64 + ll]; \
    float2 s2 = rb[(2 * 8 + kk) * 64 + ll], s3 = rb[(3 * 8 + kk) * 64 + ll]; \
    float2 sv;                                                    \
    sv.x = (s0.x + s1.x) + (s2.x + s3.x);                         \
    sv.y = (s0.y + s1.y) + (s2.y + s3.y);                         \
    *reinterpret_cast<float2*>(o + ((g) * 8 + kk) * 128 + 2 * ll) = sv; \
  }

  OCT(0, a0,  a1,  a2,  a3,  a4,  a5,  a6,  a7)
  OCT(1, a8,  a9,  a10, a11, a12, a13, a14, a15)
  OCT(2, a16, a17, a18, a19, a20, a21, a22, a23)
  OCT(3, a24, a25, a26, a27, a28, a29, a30, a31)
#undef OCT
}

// ---------------------------------------------------------------- k_reduce
// U[b,k,d] = sum_c pU[(b*nchunk+c)*2+dh][k][dl]; 512 blocks, 8 subs x 8 accs.
__global__ __launch_bounds__(256) void k_reduce(const float* __restrict__ pU,
                                                float* __restrict__ U, int nchunk) {
  int e = blockIdx.x * 32 + (threadIdx.x & 31);
  int sub = threadIdx.x >> 5;              // 0..7
  int b = e >> 13;
  int kd = e & 8191;
  int k = kd >> 8;
  int d = kd & 255;
  int dh = d >> 7, dl = d & 127;
  const float* p = pU + (size_t)b * nchunk * 8192 + (size_t)dh * 4096 + k * 128 + dl;
  float a0 = 0.f, a1 = 0.f, a2 = 0.f, a3 = 0.f;
  float a4 = 0.f, a5 = 0.f, a6 = 0.f, a7 = 0.f;
  int c = sub;
#pragma unroll 1
  for (; c + 56 < nchunk; c += 64) {
    a0 += p[(size_t)c * 8192];
    a1 += p[(size_t)(c + 8) * 8192];
    a2 += p[(size_t)(c + 16) * 8192];
    a3 += p[(size_t)(c + 24) * 8192];
    a4 += p[(size_t)(c + 32) * 8192];
    a5 += p[(size_t)(c + 40) * 8192];
    a6 += p[(size_t)(c + 48) * 8192];
    a7 += p[(size_t)(c + 56) * 8192];
  }
  for (; c < nchunk; c += 8) a0 += p[(size_t)c * 8192];
  __shared__ float red[256];
  red[threadIdx.x] = ((a0 + a1) + (a2 + a3)) + ((a4 + a5) + (a6 + a7));
  __syncthreads();
  if (threadIdx.x < 32) {
    float s = red[threadIdx.x];
#pragma unroll
    for (int i = 1; i < 8; ++i) s += red[i * 32 + threadIdx.x];
    U[e] = s;
  }
}

// ---------------------------------------------------------------- k_project
__global__ __launch_bounds__(256) void k_project(
    const float* __restrict__ U, const float* __restrict__ pS,
    const float* __restrict__ Wq, const float* __restrict__ bq,
    const float* __restrict__ Wk, const float* __restrict__ bk,
    const float* __restrict__ Wv, const float* __restrict__ bv,
    const float* __restrict__ ev, const float* __restrict__ bb,
    const float* __restrict__ fw,
    float* __restrict__ Qfg, float* __restrict__ Kfg, float* __restrict__ Vfg) {
  int blk = blockIdx.x;                    // b*32 + k
  int k = blk & 31;
  int t = threadIdx.x;
  __shared__ __align__(16) float u[256];
  __shared__ float red[256];
  u[t] = U[(size_t)blk * 256 + t];
  red[t] = pS[t * 32 + k];
  __syncthreads();
#pragma unroll
  for (int off = 128; off > 0; off >>= 1) {
    if (t < off) red[t] += red[t + off];
    __syncthreads();
  }
  float sk = red[0];

  // filter response — FP64 to match numpy ref branch semantics
  float mnf = ev[0], mxf = ev[0];
#pragma unroll
  for (int i = 1; i < 32; ++i) { float v = ev[i]; mnf = fminf(mnf, v); mxf = fmaxf(mxf, v); }
  double mn = (double)mnf, mx = (double)mxf;
  double lam = ((double)ev[k] - mn) / (mx - mn + 1e-8);
  int h = t >> 5;
  float g = 0.f;
#pragma unroll
  for (int i = 0; i < 3; ++i) {
    double lo = (double)bb[h * 4 + i], hi = (double)bb[h * 4 + i + 1];
    if (lam >= lo && lam < hi) g = fw[(h * 3 + i) * 32 + k];
  }

  const float4* u4 = reinterpret_cast<const float4*>(u);
  const float4* wq4 = reinterpret_cast<const float4*>(Wq) + (size_t)t * 64;
  const float4* wk4 = reinterpret_cast<const float4*>(Wk) + (size_t)t * 64;
  const float4* wv4 = reinterpret_cast<const float4*>(Wv) + (size_t)t * 64;
  float aq = 0.f, ak = 0.f, av = 0.f;
#pragma unroll 4
  for (int j = 0; j < 64; ++j) {
    float4 uv = u4[j];
    float4 q = wq4[j], kk = wk4[j], vv = wv4[j];
    aq = fmaf(uv.x, q.x, aq);  aq = fmaf(uv.y, q.y, aq);
    aq = fmaf(uv.z, q.z, aq);  aq = fmaf(uv.w, q.w, aq);
    ak = fmaf(uv.x, kk.x, ak); ak = fmaf(uv.y, kk.y, ak);
    ak = fmaf(uv.z, kk.z, ak); ak = fmaf(uv.w, kk.w, ak);
    av = fmaf(uv.x, vv.x, av); av = fmaf(uv.y, vv.y, av);
    av = fmaf(uv.z, vv.z, av); av = fmaf(uv.w, vv.w, av);
  }
  Qfg[(size_t)blk * 256 + t] = (aq + bq[t] * sk) * g;
  Kfg[(size_t)blk * 256 + t] = (ak + bk[t] * sk) * g;
  Vfg[(size_t)blk * 256 + t] = (av + bv[t] * sk) * g;
}

// ---------------------------------------------------------------- k_attn
__global__ __launch_bounds__(1024) void k_attn(const float* __restrict__ Qfg,
                                               const float* __restrict__ Kfg,
                                               const float* __restrict__ Vfg,
                                               float* __restrict__ of) {
  int blk = blockIdx.x;                    // b*8 + h
  int b = blk >> 3, h = blk & 7;
  int tid = threadIdx.x;
  int row = tid >> 5, col = tid & 31;
  __shared__ float Q[32][33], Kt[32][33], V[32][33], A[32][33];
  size_t base = (size_t)b * 32 * 256 + h * 32;
  Q[row][col]  = Qfg[base + row * 256 + col];
  Kt[row][col] = Kfg[base + row * 256 + col];
  V[row][col]  = Vfg[base + row * 256 + col];
  __syncthreads();
  float sc = 0.f;
#pragma unroll
  for (int d0 = 0; d0 < 32; ++d0) sc = fmaf(Q[row][d0], Kt[col][d0], sc);
  sc *= 0.17677669529663687f;              // 1/sqrt(32)
  float m = sc;
#pragma unroll
  for (int o = 16; o > 0; o >>= 1) m = fmaxf(m, __shfl_xor(m, o, 32));
  float p = expf(sc - m);
  float su = p;
#pragma unroll
  for (int o = 16; o > 0; o >>= 1) su += __shfl_xor(su, o, 32);
  A[row][col] = p / su;
  __syncthreads();
  float o_ = 0.f;
#pragma unroll
  for (int l = 0; l < 32; ++l) o_ = fmaf(A[row][l], V[l][col], o_);
  of[base + row * 256 + col] = o_;
}

// ---------------------------------------------------------------- k_expand
// out[b,n,d] = sum_k E[n,k] * of[b,k,d]. Thread owns d=t, computes BOTH b
// (of in 32 float2 regs). E tile in LDS, broadcast ds_read per row.
__global__ __launch_bounds__(256) void k_expand(const float* __restrict__ E,
                                                const float* __restrict__ of,
                                                float* __restrict__ out,
                                                int N, int rows) {
  int n0 = blockIdx.x * rows;
  int n1 = n0 + rows; if (n1 > N) n1 = N;
  int nrows = n1 - n0;
  if (nrows <= 0) return;
  int t = threadIdx.x;

  const float* ofb = of + t;               // fk = {of[0][k][t], of[1][k][t]}
#define LDF(i) float2 f##i = make_float2(ofb[(i) * 256], ofb[8192 + (i) * 256]);
  LDF(0)  LDF(1)  LDF(2)  LDF(3)  LDF(4)  LDF(5)  LDF(6)  LDF(7)
  LDF(8)  LDF(9)  LDF(10) LDF(11) LDF(12) LDF(13) LDF(14) LDF(15)
  LDF(16) LDF(17) LDF(18) LDF(19) LDF(20) LDF(21) LDF(22) LDF(23)
  LDF(24) LDF(25) LDF(26) LDF(27) LDF(28) LDF(29) LDF(30) LDF(31)
#undef LDF

  __shared__ __align__(16) float Elds[50 * 32];    // rows <= 50
  {
    const float4* Esrc = reinterpret_cast<const float4*>(E + (size_t)n0 * 32);
    float4* Edst = reinterpret_cast<float4*>(Elds);
    int nf4 = nrows * 8;
    for (int i = t; i < nf4; i += 256) Edst[i] = Esrc[i];
  }
  __syncthreads();

  float* o0 = out + t;
  float* o1 = out + (size_t)N * D + t;

#define EXP2(s, fk) { acc0 = fmaf(s, fk.x, acc0); acc1 = fmaf(s, fk.y, acc1); }
#pragma unroll 1
  for (int i = 0; i < nrows; ++i) {
    const float4* er = reinterpret_cast<const float4*>(Elds + i * 32);
    float4 e0 = er[0], e1 = er[1], e2 = er[2], e3 = er[3];
    float4 e4 = er[4], e5 = er[5], e6 = er[6], e7 = er[7];
    float acc0 = 0.f, acc1 = 0.f;
    EXP2(e0.x, f0)  EXP2(e0.y, f1)  EXP2(e0.z, f2)  EXP2(e0.w, f3)
    EXP2(e1.x, f4)  EXP2(e1.y, f5)  EXP2(e1.z, f6)  EXP2(e1.w, f7)
    EXP2(e2.x, f8)  EXP2(e2.y, f9)  EXP2(e2.z, f10) EXP2(e2.w, f11)
    EXP2(e3.x, f12) EXP2(e3.y, f13) EXP2(e3.z, f14) EXP2(e3.w, f15)
    EXP2(e4.x, f16) EXP2(e4.y, f17) EXP2(e4.z, f18) EXP2(e4.w, f19)
    EXP2(e5.x, f20) EXP2(e5.y, f21) EXP2(e5.z, f22) EXP2(e5.w, f23)
    EXP2(e6.x, f24) EXP2(e6.y, f25) EXP2(e6.z, f26) EXP2(e6.w, f27)
    EXP2(e7.x, f28) EXP2(e7.y, f29) EXP2(e7.z, f30) EXP2(e7.w, f31)
    size_t roff = (size_t)(n0 + i) * D;
    o0[roff] = acc0;
    o1[roff] = acc1;
  }
#undef EXP2
}

// ---------------------------------------------------------------- launch
extern "C" void kernel_launch(void* const* d_in, const int* in_sizes, int n_in,
                              void* d_out, int out_size, void* d_ws, size_t ws_size,
                              hipStream_t stream) {
  const float* x  = (const float*)d_in[0];
  const float* E  = (const float*)d_in[1];
  const float* ev = (const float*)d_in[2];
  const float* Wq = (const float*)d_in[3];
  const float* bq = (const float*)d_in[4];
  const float* Wk = (const float*)d_in[5];
  const float* bk = (const float*)d_in[6];
  const float* Wv = (const float*)d_in[7];
  const float* bv = (const float*)d_in[8];
  const float* bb = (const float*)d_in[9];
  const float* fw = (const float*)d_in[10];
  float* out = (float*)d_out;
  float* ws  = (float*)d_ws;

  const int N = in_sizes[1] / 32;          // 50000
  const int B = in_sizes[0] / (N * 256);   // 2

  // workspace layout (floats)
  float* U   = ws;                         // B*32*256 = 16384
  float* Qfg = ws + 16384;
  float* Kfg = ws + 32768;
  float* Vfg = ws + 49152;
  float* of  = ws + 65536;
  float* pS  = ws + 81920;                 // 256*32 = 8192
  float* pU  = ws + 90112;                 // B*nchunk*2*4096 floats

  // nchunk = 512 -> grid 2048 (8 blocks/CU), pU 33.6 MB (fit since r6).
  int nchunk = 512;
  if ((90112 + (size_t)B * nchunk * 8192) * sizeof(float) > ws_size) nchunk = 256;
  int rpc = (N + nchunk - 1) / nchunk;

  k_colsum<<<256, 256, 0, stream>>>(E, pS, N);
  k_partial<<<B * nchunk * 2, 256, 0, stream>>>(x, E, pU, N, nchunk, rpc);
  k_reduce<<<B * 8192 / 32, 256, 0, stream>>>(pU, U, nchunk);
  k_project<<<B * 32, 256, 0, stream>>>(U, pS, Wq, bq, Wk, bk, Wv, bv,
                                        ev, bb, fw, Qfg, Kfg, Vfg);
  k_attn<<<B * 8, 1024, 0, stream>>>(Qfg, Kfg, Vfg, of);
  int rows = 50;
  int nbr = (N + rows - 1) / rows;
  k_expand<<<nbr, 256, 0, stream>>>(E, of, out, N, rows);
}